// Round 7
// baseline (342.566 us; speedup 1.0000x reference)
//
#include <hip/hip_runtime.h>

typedef unsigned short u16;
typedef unsigned int u32;
typedef __attribute__((ext_vector_type(8))) short s16x8;
typedef __attribute__((ext_vector_type(4))) float f32x4;
typedef __attribute__((ext_vector_type(4))) u16   u16x4;
typedef __attribute__((ext_vector_type(2))) u32   u32x2;

// ---- helpers ----
__device__ __forceinline__ u16 f2bf(float f) {
    unsigned u = __builtin_bit_cast(unsigned, f);
    unsigned r = (u + 0x7fffu + ((u >> 16) & 1u)) >> 16;
    return (u16)r;
}

__device__ __forceinline__ u32 cvt_pk_bf16(float a, float b) {
    u32 r;
    asm("v_cvt_pk_bf16_f32 %0, %1, %2" : "=v"(r) : "v"(a), "v"(b));
    return r;
}

__device__ __forceinline__ void gload_lds16(const u16* gp, u16* lp) {
    __builtin_amdgcn_global_load_lds(
        (const __attribute__((address_space(1))) unsigned*)(const void*)gp,
        (__attribute__((address_space(3))) unsigned*)(void*)lp,
        16, 0, 0);
}

// ---- fused f32 -> bf16 convert: H (2M quads) + 4 weights (256K quads each) ----
__global__ __launch_bounds__(256) void cvt_all(const float* __restrict__ H,
        const float* __restrict__ Wq, const float* __restrict__ Wk,
        const float* __restrict__ Wv, const float* __restrict__ Wo,
        u16* __restrict__ Hb, u16* __restrict__ Wqb, u16* __restrict__ Wkb,
        u16* __restrict__ Wvb, u16* __restrict__ Wob) {
    int i = blockIdx.x * blockDim.x + threadIdx.x;   // quad index
    const float* s; u16* d; int o;
    if (i < 2097152) { s = H; d = Hb; o = i; }
    else {
        int j = i - 2097152;
        int a = j >> 18; o = j & 262143;
        s = a == 0 ? Wq : a == 1 ? Wk : a == 2 ? Wv : Wo;
        d = a == 0 ? Wqb : a == 1 ? Wkb : a == 2 ? Wvb : Wob;
    }
    f32x4 f = ((const f32x4*)s)[o];
    u32x2 v;
    v[0] = cvt_pk_bf16(f[0], f[1]);
    v[1] = cvt_pk_bf16(f[2], f[3]);
    ((u32x2*)d)[o] = v;
}

// ---- fused QKV GEMM: C[m][n] = sum_k A[m][k]*B[n][k]; per-block output select ----
// which = blockIdx.x>>3: 0->Q (scaled, [b,h,s,d]), 1->K ([b,h,s,d]), 2->V^T ([b,h,d,s])
__global__ __launch_bounds__(256) void gemm_qkv(const u16* __restrict__ A,
        const u16* __restrict__ B0, const u16* __restrict__ B1, const u16* __restrict__ B2,
        const float* __restrict__ c0, const float* __restrict__ c1, const float* __restrict__ c2,
        u16* __restrict__ O0, u16* __restrict__ O1, u16* __restrict__ O2) {
    __shared__ __align__(16) u16 As[2][128 * 64];
    __shared__ __align__(16) u16 Bs[2][128 * 64];
    const int tid  = threadIdx.x;
    const int w    = tid >> 6, lane = tid & 63;
    const int l15  = lane & 15, g = lane >> 4;
    const int wr   = w >> 1, wc = w & 1;
    const int which = blockIdx.x >> 3;
    const int bm0  = blockIdx.y * 128, bn0 = (blockIdx.x & 7) * 128;
    const u16* Bp     = which == 0 ? B0 : which == 1 ? B1 : B2;
    const float* bias = which == 0 ? c0 : which == 1 ? c1 : c2;
    u16* outp         = which == 0 ? O0 : which == 1 ? O1 : O2;
    const float scale = which == 0 ? 0.18033688011112042f : 1.0f;  // (1/8)*log2(e)

    // per-lane staging sources (chunk swizzled)
    const u16* asrc[4]; const u16* bsrc[4];
#pragma unroll
    for (int i = 0; i < 4; ++i) {
        int c = (w * 4 + i) * 64 + lane;
        int row = c >> 3, kc = (c & 7) ^ (row & 7);
        asrc[i] = A  + (size_t)(bm0 + row) * 1024 + kc * 8;
        bsrc[i] = Bp + (size_t)(bn0 + row) * 1024 + kc * 8;
    }
    auto stage = [&](int buf, int kt) {
#pragma unroll
        for (int i = 0; i < 4; ++i) {
            gload_lds16(asrc[i] + kt * 64, &As[buf][(w * 4 + i) * 512]);
            gload_lds16(bsrc[i] + kt * 64, &Bs[buf][(w * 4 + i) * 512]);
        }
    };

    f32x4 acc[4][4] = {};
    stage(0, 0);

#pragma unroll 2
    for (int kt = 0; kt < 16; ++kt) {
        const int cur = kt & 1;
        if (kt < 15) {
            stage(cur ^ 1, kt + 1);
            asm volatile("s_waitcnt vmcnt(8)" ::: "memory");
        } else {
            asm volatile("s_waitcnt vmcnt(0)" ::: "memory");
        }
        __builtin_amdgcn_s_barrier();
        __builtin_amdgcn_sched_barrier(0);

#pragma unroll
        for (int kk = 0; kk < 2; ++kk) {
            s16x8 af[4], bf_[4];
#pragma unroll
            for (int mi = 0; mi < 4; ++mi) {
                int row = wr * 64 + mi * 16 + l15;
                af[mi] = *(const s16x8*)&As[cur][row * 64 + (((kk * 4 + g) ^ (row & 7)) << 3)];
            }
#pragma unroll
            for (int ni = 0; ni < 4; ++ni) {
                int row = wc * 64 + ni * 16 + l15;
                bf_[ni] = *(const s16x8*)&Bs[cur][row * 64 + (((kk * 4 + g) ^ (row & 7)) << 3)];
            }
#pragma unroll
            for (int mi = 0; mi < 4; ++mi)
#pragma unroll
                for (int ni = 0; ni < 4; ++ni)
                    acc[mi][ni] = __builtin_amdgcn_mfma_f32_16x16x32_bf16(af[mi], bf_[ni], acc[mi][ni], 0, 0, 0);
        }
        __builtin_amdgcn_sched_barrier(0);
        __builtin_amdgcn_s_barrier();
    }

#pragma unroll
    for (int mi = 0; mi < 4; ++mi) {
#pragma unroll
        for (int ni = 0; ni < 4; ++ni) {
            int ncol = bn0 + wc * 64 + ni * 16 + l15;
            float bv = bias[ncol];
#pragma unroll
            for (int r = 0; r < 4; ++r) {
                int m   = bm0 + wr * 64 + mi * 16 + g * 4 + r;
                float v = (acc[mi][ni][r] + bv) * scale;
                int b_ = m >> 11, s = m & 2047, h = ncol >> 6, d = ncol & 63;
                if (which == 2)
                    outp[(((size_t)(b_ * 16 + h)) * 64 + d) * 2048 + s] = f2bf(v);
                else
                    outp[(((size_t)(b_ * 16 + h)) * 2048 + s) * 64 + d] = f2bf(v);
            }
        }
    }
}

// ---- output GEMM: f32 out, linear [m][n] ----
__global__ __launch_bounds__(256) void gemm_out(const u16* __restrict__ A, const u16* __restrict__ B,
                                                const float* __restrict__ bias, float* __restrict__ outp) {
    __shared__ __align__(16) u16 As[2][128 * 64];
    __shared__ __align__(16) u16 Bs[2][128 * 64];
    const int tid  = threadIdx.x;
    const int w    = tid >> 6, lane = tid & 63;
    const int l15  = lane & 15, g = lane >> 4;
    const int wr   = w >> 1, wc = w & 1;
    const int bm0  = blockIdx.y * 128, bn0 = blockIdx.x * 128;

    const u16* asrc[4]; const u16* bsrc[4];
#pragma unroll
    for (int i = 0; i < 4; ++i) {
        int c = (w * 4 + i) * 64 + lane;
        int row = c >> 3, kc = (c & 7) ^ (row & 7);
        asrc[i] = A + (size_t)(bm0 + row) * 1024 + kc * 8;
        bsrc[i] = B + (size_t)(bn0 + row) * 1024 + kc * 8;
    }
    auto stage = [&](int buf, int kt) {
#pragma unroll
        for (int i = 0; i < 4; ++i) {
            gload_lds16(asrc[i] + kt * 64, &As[buf][(w * 4 + i) * 512]);
            gload_lds16(bsrc[i] + kt * 64, &Bs[buf][(w * 4 + i) * 512]);
        }
    };

    f32x4 acc[4][4] = {};
    stage(0, 0);

#pragma unroll 2
    for (int kt = 0; kt < 16; ++kt) {
        const int cur = kt & 1;
        if (kt < 15) {
            stage(cur ^ 1, kt + 1);
            asm volatile("s_waitcnt vmcnt(8)" ::: "memory");
        } else {
            asm volatile("s_waitcnt vmcnt(0)" ::: "memory");
        }
        __builtin_amdgcn_s_barrier();
        __builtin_amdgcn_sched_barrier(0);

#pragma unroll
        for (int kk = 0; kk < 2; ++kk) {
            s16x8 af[4], bf_[4];
#pragma unroll
            for (int mi = 0; mi < 4; ++mi) {
                int row = wr * 64 + mi * 16 + l15;
                af[mi] = *(const s16x8*)&As[cur][row * 64 + (((kk * 4 + g) ^ (row & 7)) << 3)];
            }
#pragma unroll
            for (int ni = 0; ni < 4; ++ni) {
                int row = wc * 64 + ni * 16 + l15;
                bf_[ni] = *(const s16x8*)&Bs[cur][row * 64 + (((kk * 4 + g) ^ (row & 7)) << 3)];
            }
#pragma unroll
            for (int mi = 0; mi < 4; ++mi)
#pragma unroll
                for (int ni = 0; ni < 4; ++ni)
                    acc[mi][ni] = __builtin_amdgcn_mfma_f32_16x16x32_bf16(af[mi], bf_[ni], acc[mi][ni], 0, 0, 0);
        }
        __builtin_amdgcn_sched_barrier(0);
        __builtin_amdgcn_s_barrier();
    }

#pragma unroll
    for (int mi = 0; mi < 4; ++mi) {
#pragma unroll
        for (int ni = 0; ni < 4; ++ni) {
            int ncol = bn0 + wc * 64 + ni * 16 + l15;
            float bv = bias[ncol];
#pragma unroll
            for (int r = 0; r < 4; ++r) {
                int m = bm0 + wr * 64 + mi * 16 + g * 4 + r;
                outp[(size_t)m * 1024 + ncol] = acc[mi][ni][r] + bv;
            }
        }
    }
}

// ---- flash attention: max-tracking softmax (R5-exact), 32 q/wave, 2-phase pipelined ----
// Q[bh][s][d] pre-scaled by log2e/8, K[bh][s][d], VT[bh][d][s] -> concat bf16 [b][s][e]
__global__ __launch_bounds__(256) void attn_kernel(const u16* __restrict__ Q, const u16* __restrict__ K,
                                                   const u16* __restrict__ VT, u16* __restrict__ C) {
    __shared__ __align__(16) u16 Ks[2][64 * 64];
    __shared__ __align__(16) u16 Vs[2][64 * 64];
    __shared__ __align__(16) u16 Ps[4][32 * 64];   // per-wave 32 q-rows x 64 keys
    const int tid = threadIdx.x;
    const int w   = tid >> 6, lane = tid & 63;
    const int l15 = lane & 15, g = lane >> 4;
    const int bh  = blockIdx.x >> 4;
    const int qt  = blockIdx.x & 15;
    const u16* Qb = Q  + (size_t)bh * 2048 * 64;
    const u16* Kb = K  + (size_t)bh * 2048 * 64;
    const u16* Vb = VT + (size_t)bh * 64 * 2048;
    const int q0  = qt * 128 + w * 32;

    // Q rows as B-fragments (col=q): bq[qg][kk]
    s16x8 bq[2][2];
#pragma unroll
    for (int qg = 0; qg < 2; ++qg)
#pragma unroll
        for (int kk = 0; kk < 2; ++kk)
            bq[qg][kk] = *(const s16x8*)&Qb[(size_t)(q0 + qg * 16 + l15) * 64 + kk * 32 + g * 8];

    // per-lane staging sources (chunk swizzled)
    const u16* ksrc[2]; const u16* vsrc[2];
#pragma unroll
    for (int i = 0; i < 2; ++i) {
        int c = w * 128 + i * 64 + lane;
        int rt = c >> 3, cc = (c & 7) ^ (rt & 7);
        ksrc[i] = Kb + (size_t)rt * 64 + cc * 8;
        vsrc[i] = Vb + (size_t)rt * 2048 + cc * 8;
    }
    auto stage = [&](int buf, int kt) {
        int kb = kt * 64;
#pragma unroll
        for (int i = 0; i < 2; ++i) {
            gload_lds16(ksrc[i] + (size_t)kb * 64, &Ks[buf][(w * 128 + i * 64) * 8]);
            gload_lds16(vsrc[i] + kb,              &Vs[buf][(w * 128 + i * 64) * 8]);
        }
    };

    float m_[2] = {-1e30f, -1e30f};
    float l_[2] = {0.f, 0.f};          // lane-local partial (this lane's g-slice of keys)
    f32x4 accO[2][4] = {};             // accO[qg][jd][r] = O[q=q0+qg*16+l15][d=jd*16+g*4+r]
    stage(0, 0);

#pragma unroll 2
    for (int kt = 0; kt < 32; ++kt) {
        const int cur = kt & 1;
        if (kt < 31) {
            stage(cur ^ 1, kt + 1);
            asm volatile("s_waitcnt vmcnt(4)" ::: "memory");
        } else {
            asm volatile("s_waitcnt vmcnt(0)" ::: "memory");
        }
        __builtin_amdgcn_s_barrier();
        __builtin_amdgcn_sched_barrier(0);

        // S^T = K . Q^T : lane holds S[q=qg*16+l15][k = kj*16 + g*4 + r]
        f32x4 sc[2][4];
        __builtin_amdgcn_s_setprio(1);
#pragma unroll
        for (int kj = 0; kj < 4; ++kj) {
            f32x4 z0 = {}, z1 = {};
#pragma unroll
            for (int kk = 0; kk < 2; ++kk) {
                int row  = kj * 16 + l15;
                s16x8 ak = *(const s16x8*)&Ks[cur][row * 64 + (((kk * 4 + g) ^ (l15 & 7)) << 3)];
                z0 = __builtin_amdgcn_mfma_f32_16x16x32_bf16(ak, bq[0][kk], z0, 0, 0, 0);
                z1 = __builtin_amdgcn_mfma_f32_16x16x32_bf16(ak, bq[1][kk], z1, 0, 0, 0);
            }
            sc[0][kj] = z0; sc[1][kj] = z1;
        }
        __builtin_amdgcn_s_setprio(0);

        // row max per q-group (reduced across g -> row-uniform)
        float t_[2];
#pragma unroll
        for (int qg = 0; qg < 2; ++qg) {
            float a0 = fmaxf(fmaxf(sc[qg][0][0], sc[qg][0][1]), fmaxf(sc[qg][0][2], sc[qg][0][3]));
            float a1 = fmaxf(fmaxf(sc[qg][1][0], sc[qg][1][1]), fmaxf(sc[qg][1][2], sc[qg][1][3]));
            float a2 = fmaxf(fmaxf(sc[qg][2][0], sc[qg][2][1]), fmaxf(sc[qg][2][2], sc[qg][2][3]));
            float a3 = fmaxf(fmaxf(sc[qg][3][0], sc[qg][3][1]), fmaxf(sc[qg][3][2], sc[qg][3][3]));
            float a  = fmaxf(fmaxf(a0, a1), fmaxf(a2, a3));
            a = fmaxf(a, __shfl_xor(a, 16));
            a = fmaxf(a, __shfl_xor(a, 32));
            t_[qg] = a;
        }

        const bool grow = __any((t_[0] > m_[0]) || (t_[1] > m_[1]));   // wave-uniform; exact skip
        if (grow) {
#pragma unroll
            for (int qg = 0; qg < 2; ++qg) {
                float mn    = fmaxf(m_[qg], t_[qg]);
                float alpha = __builtin_amdgcn_exp2f(m_[qg] - mn);   // ==1 for non-growing rows
                m_[qg] = mn;
                l_[qg] *= alpha;
#pragma unroll
                for (int jd = 0; jd < 4; ++jd)
#pragma unroll
                    for (int r = 0; r < 4; ++r) accO[qg][jd][r] *= alpha;
            }
        }

        // p = exp2(s - m); lane-local l accumulation; pack to LDS
#pragma unroll
        for (int qg = 0; qg < 2; ++qg) {
            int prow = qg * 16 + l15;
            float mq = m_[qg];
#pragma unroll
            for (int kj = 0; kj < 4; ++kj) {
                float p0 = __builtin_amdgcn_exp2f(sc[qg][kj][0] - mq);
                float p1 = __builtin_amdgcn_exp2f(sc[qg][kj][1] - mq);
                float p2 = __builtin_amdgcn_exp2f(sc[qg][kj][2] - mq);
                float p3 = __builtin_amdgcn_exp2f(sc[qg][kj][3] - mq);
                l_[qg] += (p0 + p1) + (p2 + p3);
                int cs = (kj * 4 + g) ^ ((l15 & 7) << 1);
                u32x2 v;
                v[0] = cvt_pk_bf16(p0, p1);
                v[1] = cvt_pk_bf16(p2, p3);
                *(u32x2*)&Ps[w][prow * 64 + cs * 4] = v;
            }
        }

        // P fragments back (B-frag: row q, k-slice)
        s16x8 pf[2][2];
#pragma unroll
        for (int qg = 0; qg < 2; ++qg)
#pragma unroll
            for (int kk = 0; kk < 2; ++kk) {
                int c0 = (kk * 8 + g * 2) ^ ((l15 & 7) << 1);
                pf[qg][kk] = *(const s16x8*)&Ps[w][(qg * 16 + l15) * 64 + c0 * 4];
            }

        // O^T += V^T . P^T  (av shared across both q-groups)
        __builtin_amdgcn_s_setprio(1);
#pragma unroll
        for (int jd = 0; jd < 4; ++jd) {
#pragma unroll
            for (int kk = 0; kk < 2; ++kk) {
                int row  = jd * 16 + l15;
                s16x8 av = *(const s16x8*)&Vs[cur][row * 64 + (((kk * 4 + g) ^ (l15 & 7)) << 3)];
                accO[0][jd] = __builtin_amdgcn_mfma_f32_16x16x32_bf16(av, pf[0][kk], accO[0][jd], 0, 0, 0);
                accO[1][jd] = __builtin_amdgcn_mfma_f32_16x16x32_bf16(av, pf[1][kk], accO[1][jd], 0, 0, 0);
            }
        }
        __builtin_amdgcn_s_setprio(0);
        __builtin_amdgcn_sched_barrier(0);
        __builtin_amdgcn_s_barrier();
    }

    const int b_ = bh >> 4, h = bh & 15;
#pragma unroll
    for (int qg = 0; qg < 2; ++qg) {
        float lt = l_[qg];
        lt += __shfl_xor(lt, 16);
        lt += __shfl_xor(lt, 32);
        float inv = 1.0f / lt;
        int s = q0 + qg * 16 + l15;
#pragma unroll
        for (int jd = 0; jd < 4; ++jd) {
            u32x2 v;
            v[0] = cvt_pk_bf16(accO[qg][jd][0] * inv, accO[qg][jd][1] * inv);
            v[1] = cvt_pk_bf16(accO[qg][jd][2] * inv, accO[qg][jd][3] * inv);
            *(u32x2*)&C[((size_t)(b_ * 2048 + s)) * 1024 + h * 64 + jd * 16 + g * 4] = v;
        }
    }
}

extern "C" void kernel_launch(void* const* d_in, const int* in_sizes, int n_in,
                              void* d_out, int out_size, void* d_ws, size_t ws_size,
                              hipStream_t stream) {
    const float* H  = (const float*)d_in[0];
    const float* Wq = (const float*)d_in[1];
    const float* bq = (const float*)d_in[2];
    const float* Wk = (const float*)d_in[3];
    const float* bk = (const float*)d_in[4];
    const float* Wv = (const float*)d_in[5];
    const float* bv = (const float*)d_in[6];
    const float* Wo = (const float*)d_in[7];
    const float* bo = (const float*)d_in[8];

    char*  ws  = (char*)d_ws;
    size_t off = 0;
    auto alloc = [&](size_t elems) { u16* p = (u16*)(ws + off); off += elems * 2; return p; };
    u16* Hb  = alloc((size_t)8192 * 1024);
    u16* Wqb = alloc((size_t)1024 * 1024);
    u16* Wkb = alloc((size_t)1024 * 1024);
    u16* Wvb = alloc((size_t)1024 * 1024);
    u16* Wob = alloc((size_t)1024 * 1024);
    u16* Qs  = alloc((size_t)8192 * 1024);
    u16* Ks  = alloc((size_t)8192 * 1024);
    u16* VTs = alloc((size_t)8192 * 1024);
    u16* Cc  = alloc((size_t)8192 * 1024);

    cvt_all<<<12288, 256, 0, stream>>>(H, Wq, Wk, Wv, Wo, Hb, Wqb, Wkb, Wvb, Wob);

    dim3 gq(24, 64);
    gemm_qkv<<<gq, 256, 0, stream>>>(Hb, Wqb, Wkb, Wvb, bq, bk, bv, Qs, Ks, VTs);

    attn_kernel<<<1024, 256, 0, stream>>>(Qs, Ks, VTs, Cc);

    dim3 gg(8, 64);
    gemm_out<<<gg, 256, 0, stream>>>(Cc, Wob, bo, (float*)d_out);
}

// Round 8
// 332.495 us; speedup vs baseline: 1.0303x; 1.0303x over previous
//
#include <hip/hip_runtime.h>

typedef unsigned short u16;
typedef unsigned int u32;
typedef __attribute__((ext_vector_type(8))) short s16x8;
typedef __attribute__((ext_vector_type(4))) float f32x4;
typedef __attribute__((ext_vector_type(16))) float f32x16;
typedef __attribute__((ext_vector_type(4))) u16   u16x4;
typedef __attribute__((ext_vector_type(2))) u32   u32x2;
typedef __attribute__((ext_vector_type(4))) u32   u32x4;

// ---- helpers ----
__device__ __forceinline__ u16 f2bf(float f) {
    unsigned u = __builtin_bit_cast(unsigned, f);
    unsigned r = (u + 0x7fffu + ((u >> 16) & 1u)) >> 16;
    return (u16)r;
}

__device__ __forceinline__ u32 cvt_pk_bf16(float a, float b) {
    u32 r;
    asm("v_cvt_pk_bf16_f32 %0, %1, %2" : "=v"(r) : "v"(a), "v"(b));
    return r;
}

// swap: a'[hi lanes] = b[lo lanes], b'[lo lanes] = a[hi lanes]; others keep own
__device__ __forceinline__ void permswap(u32& a, u32& b) {
    asm volatile("v_permlane32_swap_b32 %0, %1" : "+v"(a), "+v"(b));
}

__device__ __forceinline__ void gload_lds16(const u16* gp, u16* lp) {
    __builtin_amdgcn_global_load_lds(
        (const __attribute__((address_space(1))) unsigned*)(const void*)gp,
        (__attribute__((address_space(3))) unsigned*)(void*)lp,
        16, 0, 0);
}

__device__ __forceinline__ float vmax16(f32x16 v) {
    float a0 = fmaxf(v[0], v[8]),  a1 = fmaxf(v[1], v[9]);
    float a2 = fmaxf(v[2], v[10]), a3 = fmaxf(v[3], v[11]);
    float a4 = fmaxf(v[4], v[12]), a5 = fmaxf(v[5], v[13]);
    float a6 = fmaxf(v[6], v[14]), a7 = fmaxf(v[7], v[15]);
    float b0 = fmaxf(a0, a4), b1 = fmaxf(a1, a5), b2 = fmaxf(a2, a6), b3 = fmaxf(a3, a7);
    return fmaxf(fmaxf(b0, b1), fmaxf(b2, b3));
}

// ---- fused f32 -> bf16 convert: H (2M quads) + 4 weights (256K quads each) ----
__global__ __launch_bounds__(256) void cvt_all(const float* __restrict__ H,
        const float* __restrict__ Wq, const float* __restrict__ Wk,
        const float* __restrict__ Wv, const float* __restrict__ Wo,
        u16* __restrict__ Hb, u16* __restrict__ Wqb, u16* __restrict__ Wkb,
        u16* __restrict__ Wvb, u16* __restrict__ Wob) {
    int i = blockIdx.x * blockDim.x + threadIdx.x;   // quad index
    const float* s; u16* d; int o;
    if (i < 2097152) { s = H; d = Hb; o = i; }
    else {
        int j = i - 2097152;
        int a = j >> 18; o = j & 262143;
        s = a == 0 ? Wq : a == 1 ? Wk : a == 2 ? Wv : Wo;
        d = a == 0 ? Wqb : a == 1 ? Wkb : a == 2 ? Wvb : Wob;
    }
    f32x4 f = ((const f32x4*)s)[o];
    u32x2 v;
    v[0] = cvt_pk_bf16(f[0], f[1]);
    v[1] = cvt_pk_bf16(f[2], f[3]);
    ((u32x2*)d)[o] = v;
}

// ---- fused QKV GEMM: C[m][n] = sum_k A[m][k]*B[n][k]; per-block output select ----
__global__ __launch_bounds__(256) void gemm_qkv(const u16* __restrict__ A,
        const u16* __restrict__ B0, const u16* __restrict__ B1, const u16* __restrict__ B2,
        const float* __restrict__ c0, const float* __restrict__ c1, const float* __restrict__ c2,
        u16* __restrict__ O0, u16* __restrict__ O1, u16* __restrict__ O2) {
    __shared__ __align__(16) u16 As[2][128 * 64];
    __shared__ __align__(16) u16 Bs[2][128 * 64];
    const int tid  = threadIdx.x;
    const int w    = tid >> 6, lane = tid & 63;
    const int l15  = lane & 15, g = lane >> 4;
    const int wr   = w >> 1, wc = w & 1;
    const int which = blockIdx.x >> 3;
    const int bm0  = blockIdx.y * 128, bn0 = (blockIdx.x & 7) * 128;
    const u16* Bp     = which == 0 ? B0 : which == 1 ? B1 : B2;
    const float* bias = which == 0 ? c0 : which == 1 ? c1 : c2;
    u16* outp         = which == 0 ? O0 : which == 1 ? O1 : O2;
    const float scale = which == 0 ? 0.18033688011112042f : 1.0f;  // (1/8)*log2(e)

    const u16* asrc[4]; const u16* bsrc[4];
#pragma unroll
    for (int i = 0; i < 4; ++i) {
        int c = (w * 4 + i) * 64 + lane;
        int row = c >> 3, kc = (c & 7) ^ (row & 7);
        asrc[i] = A  + (size_t)(bm0 + row) * 1024 + kc * 8;
        bsrc[i] = Bp + (size_t)(bn0 + row) * 1024 + kc * 8;
    }
    auto stage = [&](int buf, int kt) {
#pragma unroll
        for (int i = 0; i < 4; ++i) {
            gload_lds16(asrc[i] + kt * 64, &As[buf][(w * 4 + i) * 512]);
            gload_lds16(bsrc[i] + kt * 64, &Bs[buf][(w * 4 + i) * 512]);
        }
    };

    f32x4 acc[4][4] = {};
    stage(0, 0);

#pragma unroll 2
    for (int kt = 0; kt < 16; ++kt) {
        const int cur = kt & 1;
        if (kt < 15) {
            stage(cur ^ 1, kt + 1);
            asm volatile("s_waitcnt vmcnt(8)" ::: "memory");
        } else {
            asm volatile("s_waitcnt vmcnt(0)" ::: "memory");
        }
        __builtin_amdgcn_s_barrier();
        __builtin_amdgcn_sched_barrier(0);

#pragma unroll
        for (int kk = 0; kk < 2; ++kk) {
            s16x8 af[4], bf_[4];
#pragma unroll
            for (int mi = 0; mi < 4; ++mi) {
                int row = wr * 64 + mi * 16 + l15;
                af[mi] = *(const s16x8*)&As[cur][row * 64 + (((kk * 4 + g) ^ (row & 7)) << 3)];
            }
#pragma unroll
            for (int ni = 0; ni < 4; ++ni) {
                int row = wc * 64 + ni * 16 + l15;
                bf_[ni] = *(const s16x8*)&Bs[cur][row * 64 + (((kk * 4 + g) ^ (row & 7)) << 3)];
            }
#pragma unroll
            for (int mi = 0; mi < 4; ++mi)
#pragma unroll
                for (int ni = 0; ni < 4; ++ni)
                    acc[mi][ni] = __builtin_amdgcn_mfma_f32_16x16x32_bf16(af[mi], bf_[ni], acc[mi][ni], 0, 0, 0);
        }
        __builtin_amdgcn_sched_barrier(0);
        __builtin_amdgcn_s_barrier();
    }

#pragma unroll
    for (int mi = 0; mi < 4; ++mi) {
#pragma unroll
        for (int ni = 0; ni < 4; ++ni) {
            int ncol = bn0 + wc * 64 + ni * 16 + l15;
            float bv = bias[ncol];
#pragma unroll
            for (int r = 0; r < 4; ++r) {
                int m   = bm0 + wr * 64 + mi * 16 + g * 4 + r;
                float v = (acc[mi][ni][r] + bv) * scale;
                int b_ = m >> 11, s = m & 2047, h = ncol >> 6, d = ncol & 63;
                if (which == 2)
                    outp[(((size_t)(b_ * 16 + h)) * 64 + d) * 2048 + s] = f2bf(v);
                else
                    outp[(((size_t)(b_ * 16 + h)) * 2048 + s) * 64 + d] = f2bf(v);
            }
        }
    }
}

// ---- output GEMM: f32 out, linear [m][n] ----
__global__ __launch_bounds__(256) void gemm_out(const u16* __restrict__ A, const u16* __restrict__ B,
                                                const float* __restrict__ bias, float* __restrict__ outp) {
    __shared__ __align__(16) u16 As[2][128 * 64];
    __shared__ __align__(16) u16 Bs[2][128 * 64];
    const int tid  = threadIdx.x;
    const int w    = tid >> 6, lane = tid & 63;
    const int l15  = lane & 15, g = lane >> 4;
    const int wr   = w >> 1, wc = w & 1;
    const int bm0  = blockIdx.y * 128, bn0 = blockIdx.x * 128;

    const u16* asrc[4]; const u16* bsrc[4];
#pragma unroll
    for (int i = 0; i < 4; ++i) {
        int c = (w * 4 + i) * 64 + lane;
        int row = c >> 3, kc = (c & 7) ^ (row & 7);
        asrc[i] = A + (size_t)(bm0 + row) * 1024 + kc * 8;
        bsrc[i] = B + (size_t)(bn0 + row) * 1024 + kc * 8;
    }
    auto stage = [&](int buf, int kt) {
#pragma unroll
        for (int i = 0; i < 4; ++i) {
            gload_lds16(asrc[i] + kt * 64, &As[buf][(w * 4 + i) * 512]);
            gload_lds16(bsrc[i] + kt * 64, &Bs[buf][(w * 4 + i) * 512]);
        }
    };

    f32x4 acc[4][4] = {};
    stage(0, 0);

#pragma unroll 2
    for (int kt = 0; kt < 16; ++kt) {
        const int cur = kt & 1;
        if (kt < 15) {
            stage(cur ^ 1, kt + 1);
            asm volatile("s_waitcnt vmcnt(8)" ::: "memory");
        } else {
            asm volatile("s_waitcnt vmcnt(0)" ::: "memory");
        }
        __builtin_amdgcn_s_barrier();
        __builtin_amdgcn_sched_barrier(0);

#pragma unroll
        for (int kk = 0; kk < 2; ++kk) {
            s16x8 af[4], bf_[4];
#pragma unroll
            for (int mi = 0; mi < 4; ++mi) {
                int row = wr * 64 + mi * 16 + l15;
                af[mi] = *(const s16x8*)&As[cur][row * 64 + (((kk * 4 + g) ^ (row & 7)) << 3)];
            }
#pragma unroll
            for (int ni = 0; ni < 4; ++ni) {
                int row = wc * 64 + ni * 16 + l15;
                bf_[ni] = *(const s16x8*)&Bs[cur][row * 64 + (((kk * 4 + g) ^ (row & 7)) << 3)];
            }
#pragma unroll
            for (int mi = 0; mi < 4; ++mi)
#pragma unroll
                for (int ni = 0; ni < 4; ++ni)
                    acc[mi][ni] = __builtin_amdgcn_mfma_f32_16x16x32_bf16(af[mi], bf_[ni], acc[mi][ni], 0, 0, 0);
        }
        __builtin_amdgcn_sched_barrier(0);
        __builtin_amdgcn_s_barrier();
    }

#pragma unroll
    for (int mi = 0; mi < 4; ++mi) {
#pragma unroll
        for (int ni = 0; ni < 4; ++ni) {
            int ncol = bn0 + wc * 64 + ni * 16 + l15;
            float bv = bias[ncol];
#pragma unroll
            for (int r = 0; r < 4; ++r) {
                int m = bm0 + wr * 64 + mi * 16 + g * 4 + r;
                outp[(size_t)m * 1024 + ncol] = acc[mi][ni][r] + bv;
            }
        }
    }
}

// ---- flash attention: 32x32 MFMA, in-register P exchange (T12), exact max-tracking ----
// Q[bh][s][d] pre-scaled by log2e/8, K[bh][s][d], VT[bh][d][s] -> concat bf16 [b][s][e]
// Wave owns 32 q-rows (q = l31). S^T = K.Q^T: lane(q,hi) holds S[k=kj*32+crow(r,hi)][q],
// crow(r,hi) = (r&3)+8*(r>>2)+4*hi. PV B-frag assembled via cvt_pk + permlane32_swap.
__global__ __launch_bounds__(256, 4) void attn_kernel(const u16* __restrict__ Q, const u16* __restrict__ K,
                                                      const u16* __restrict__ VT, u16* __restrict__ C) {
    __shared__ __align__(16) u16 Ks[2][64 * 64];
    __shared__ __align__(16) u16 Vs[2][64 * 64];
    const int tid = threadIdx.x;
    const int w   = tid >> 6, lane = tid & 63;
    const int l31 = lane & 31, hi = lane >> 5;
    // XCD-locality remap: each bh's 16 q-tiles land on one XCD (assumes XCD = wgid%8)
    const int n   = blockIdx.x;
    const int bh  = (n & 7) + 8 * (n >> 7);
    const int qt  = (n >> 3) & 15;
    const u16* Qb = Q  + (size_t)bh * 2048 * 64;
    const u16* Kb = K  + (size_t)bh * 2048 * 64;
    const u16* Vb = VT + (size_t)bh * 64 * 2048;
    const int q0  = qt * 128 + w * 32;

    // Q B-frags: bq[kk][i] = Q[q0+l31][kk*16 + hi*8 + i]
    s16x8 bq[4];
#pragma unroll
    for (int kk = 0; kk < 4; ++kk)
        bq[kk] = *(const s16x8*)&Qb[(size_t)(q0 + l31) * 64 + kk * 16 + hi * 8];

    // staging sources (chunk swizzled), tiles: Ks [64 keys][64 d], Vs [64 d][64 keys]
    const u16* ksrc[2]; const u16* vsrc[2];
#pragma unroll
    for (int i = 0; i < 2; ++i) {
        int c = w * 128 + i * 64 + lane;
        int rt = c >> 3, cc = (c & 7) ^ (rt & 7);
        ksrc[i] = Kb + (size_t)rt * 64 + cc * 8;
        vsrc[i] = Vb + (size_t)rt * 2048 + cc * 8;
    }
    auto stage = [&](int buf, int kt) {
        int kb = kt * 64;
#pragma unroll
        for (int i = 0; i < 2; ++i) {
            gload_lds16(ksrc[i] + (size_t)kb * 64, &Ks[buf][(w * 128 + i * 64) * 8]);
            gload_lds16(vsrc[i] + kb,              &Vs[buf][(w * 128 + i * 64) * 8]);
        }
    };

    float m_ = -1e30f, l_ = 0.f;     // row state; l_ lane-local (this hi-half's keys)
    f32x16 accO[2] = {};             // accO[dt][r] = O[q=l31][d=dt*32+crow(r,hi)]
    stage(0, 0);

#pragma unroll 2
    for (int kt = 0; kt < 32; ++kt) {
        const int cur = kt & 1;
        if (kt < 31) {
            stage(cur ^ 1, kt + 1);
            asm volatile("s_waitcnt vmcnt(4)" ::: "memory");
        } else {
            asm volatile("s_waitcnt vmcnt(0)" ::: "memory");
        }
        __builtin_amdgcn_s_barrier();
        __builtin_amdgcn_sched_barrier(0);

        // QK^T: sc[kj] covers keys kj*32..+31 for q=l31
        f32x16 sc0 = {}, sc1 = {};
        __builtin_amdgcn_s_setprio(1);
#pragma unroll
        for (int kk = 0; kk < 4; ++kk) {
            int ch = (kk * 2 + hi) ^ (l31 & 7);
            s16x8 ak0 = *(const s16x8*)&Ks[cur][(l31)      * 64 + (ch << 3)];
            s16x8 ak1 = *(const s16x8*)&Ks[cur][(32 + l31) * 64 + (ch << 3)];
            sc0 = __builtin_amdgcn_mfma_f32_32x32x16_bf16(ak0, bq[kk], sc0, 0, 0, 0);
            sc1 = __builtin_amdgcn_mfma_f32_32x32x16_bf16(ak1, bq[kk], sc1, 0, 0, 0);
        }
        __builtin_amdgcn_s_setprio(0);

        // exact online softmax (exp2 domain), row q across lane pair (l31, l31+32)
        float t = fmaxf(vmax16(sc0), vmax16(sc1));
        t = fmaxf(t, __shfl_xor(t, 32));
        const bool grow = __any(t > m_);
        if (grow) {
            float mn    = fmaxf(m_, t);
            float alpha = __builtin_amdgcn_exp2f(m_ - mn);
            m_ = mn;
            l_ *= alpha;
#pragma unroll
            for (int r = 0; r < 16; ++r) { accO[0][r] *= alpha; accO[1][r] *= alpha; }
        }

#pragma unroll
        for (int r = 0; r < 16; ++r) sc0[r] = __builtin_amdgcn_exp2f(sc0[r] - m_);
#pragma unroll
        for (int r = 0; r < 16; ++r) sc1[r] = __builtin_amdgcn_exp2f(sc1[r] - m_);
        {
            float s0 = 0.f, s1 = 0.f, s2 = 0.f, s3 = 0.f;
#pragma unroll
            for (int r = 0; r < 16; r += 4) {
                s0 += sc0[r]; s1 += sc0[r + 1]; s2 += sc0[r + 2]; s3 += sc0[r + 3];
                s0 += sc1[r]; s1 += sc1[r + 1]; s2 += sc1[r + 2]; s3 += sc1[r + 3];
            }
            l_ += (s0 + s1) + (s2 + s3);
        }

        // pack P to bf16 pairs: c[kj][rp] = {p[2rp], p[2rp+1]}
        u32 c[2][8];
#pragma unroll
        for (int rp = 0; rp < 8; ++rp) {
            c[0][rp] = cvt_pk_bf16(sc0[2 * rp], sc0[2 * rp + 1]);
            c[1][rp] = cvt_pk_bf16(sc1[2 * rp], sc1[2 * rp + 1]);
        }
        // assemble PV B-frags: pf[ks].u32[j] = P[q][ks*16 + hi*8 + 2j .. +1]
        s16x8 pf[4];
#pragma unroll
        for (int ks = 0; ks < 4; ++ks) {
            int kj = ks >> 1, base = (ks & 1) * 4;
            u32 a0 = c[kj][base + 0], b0 = c[kj][base + 2];
            u32 a1 = c[kj][base + 1], b1 = c[kj][base + 3];
            permswap(a0, b0);
            permswap(a1, b1);
            u32x4 pv; pv[0] = a0; pv[1] = a1; pv[2] = b0; pv[3] = b1;
            pf[ks] = __builtin_bit_cast(s16x8, pv);
        }

        // O^T += V^T . P^T
        __builtin_amdgcn_s_setprio(1);
#pragma unroll
        for (int ks = 0; ks < 4; ++ks) {
            int ch = (ks * 2 + hi) ^ (l31 & 7);
            s16x8 av0 = *(const s16x8*)&Vs[cur][(l31)      * 64 + (ch << 3)];
            s16x8 av1 = *(const s16x8*)&Vs[cur][(32 + l31) * 64 + (ch << 3)];
            accO[0] = __builtin_amdgcn_mfma_f32_32x32x16_bf16(av0, pf[ks], accO[0], 0, 0, 0);
            accO[1] = __builtin_amdgcn_mfma_f32_32x32x16_bf16(av1, pf[ks], accO[1], 0, 0, 0);
        }
        __builtin_amdgcn_s_setprio(0);
        __builtin_amdgcn_sched_barrier(0);
        __builtin_amdgcn_s_barrier();
    }

    // epilogue: O[q][d] = accO/l ; d = dt*32 + 8*rq + 4*hi + e (4 consecutive per quad)
    l_ += __shfl_xor(l_, 32);
    float inv = 1.0f / l_;
    const int b_ = bh >> 4, h = bh & 15;
    const int s  = q0 + l31;
#pragma unroll
    for (int dt = 0; dt < 2; ++dt)
#pragma unroll
        for (int rq = 0; rq < 4; ++rq) {
            int d0 = dt * 32 + 8 * rq + 4 * hi;
            u32x2 v;
            v[0] = cvt_pk_bf16(accO[dt][4 * rq] * inv,     accO[dt][4 * rq + 1] * inv);
            v[1] = cvt_pk_bf16(accO[dt][4 * rq + 2] * inv, accO[dt][4 * rq + 3] * inv);
            *(u32x2*)&C[((size_t)(b_ * 2048 + s)) * 1024 + h * 64 + d0] = v;
        }
}

extern "C" void kernel_launch(void* const* d_in, const int* in_sizes, int n_in,
                              void* d_out, int out_size, void* d_ws, size_t ws_size,
                              hipStream_t stream) {
    const float* H  = (const float*)d_in[0];
    const float* Wq = (const float*)d_in[1];
    const float* bq = (const float*)d_in[2];
    const float* Wk = (const float*)d_in[3];
    const float* bk = (const float*)d_in[4];
    const float* Wv = (const float*)d_in[5];
    const float* bv = (const float*)d_in[6];
    const float* Wo = (const float*)d_in[7];
    const float* bo = (const float*)d_in[8];

    char*  ws  = (char*)d_ws;
    size_t off = 0;
    auto alloc = [&](size_t elems) { u16* p = (u16*)(ws + off); off += elems * 2; return p; };
    u16* Hb  = alloc((size_t)8192 * 1024);
    u16* Wqb = alloc((size_t)1024 * 1024);
    u16* Wkb = alloc((size_t)1024 * 1024);
    u16* Wvb = alloc((size_t)1024 * 1024);
    u16* Wob = alloc((size_t)1024 * 1024);
    u16* Qs  = alloc((size_t)8192 * 1024);
    u16* Ks  = alloc((size_t)8192 * 1024);
    u16* VTs = alloc((size_t)8192 * 1024);
    u16* Cc  = alloc((size_t)8192 * 1024);

    cvt_all<<<12288, 256, 0, stream>>>(H, Wq, Wk, Wv, Wo, Hb, Wqb, Wkb, Wvb, Wob);

    dim3 gq(24, 64);
    gemm_qkv<<<gq, 256, 0, stream>>>(Hb, Wqb, Wkb, Wvb, bq, bk, bv, Qs, Ks, VTs);

    attn_kernel<<<1024, 256, 0, stream>>>(Qs, Ks, VTs, Cc);

    dim3 gg(8, 64);
    gemm_out<<<gg, 256, 0, stream>>>(Cc, Wob, bo, (float*)d_out);
}

// Round 9
// 315.048 us; speedup vs baseline: 1.0873x; 1.0554x over previous
//
#include <hip/hip_runtime.h>

typedef unsigned short u16;
typedef unsigned int u32;
typedef __attribute__((ext_vector_type(8))) short s16x8;
typedef __attribute__((ext_vector_type(4))) float f32x4;
typedef __attribute__((ext_vector_type(16))) float f32x16;
typedef __attribute__((ext_vector_type(4))) u16   u16x4;
typedef __attribute__((ext_vector_type(2))) u32   u32x2;
typedef __attribute__((ext_vector_type(4))) u32   u32x4;

// ---- helpers ----
__device__ __forceinline__ u16 f2bf(float f) {
    unsigned u = __builtin_bit_cast(unsigned, f);
    unsigned r = (u + 0x7fffu + ((u >> 16) & 1u)) >> 16;
    return (u16)r;
}

__device__ __forceinline__ u32 cvt_pk_bf16(float a, float b) {
    u32 r;
    asm("v_cvt_pk_bf16_f32 %0, %1, %2" : "=v"(r) : "v"(a), "v"(b));
    return r;
}

// swap: a'[hi lanes] = b[lo lanes], b'[lo lanes] = a[hi lanes]; others keep own
__device__ __forceinline__ void permswap(u32& a, u32& b) {
    asm volatile("v_permlane32_swap_b32 %0, %1" : "+v"(a), "+v"(b));
}

__device__ __forceinline__ void gload_lds16(const u16* gp, u16* lp) {
    __builtin_amdgcn_global_load_lds(
        (const __attribute__((address_space(1))) unsigned*)(const void*)gp,
        (__attribute__((address_space(3))) unsigned*)(void*)lp,
        16, 0, 0);
}

__device__ __forceinline__ float vmax16(f32x16 v) {
    float a0 = fmaxf(v[0], v[8]),  a1 = fmaxf(v[1], v[9]);
    float a2 = fmaxf(v[2], v[10]), a3 = fmaxf(v[3], v[11]);
    float a4 = fmaxf(v[4], v[12]), a5 = fmaxf(v[5], v[13]);
    float a6 = fmaxf(v[6], v[14]), a7 = fmaxf(v[7], v[15]);
    float b0 = fmaxf(a0, a4), b1 = fmaxf(a1, a5), b2 = fmaxf(a2, a6), b3 = fmaxf(a3, a7);
    return fmaxf(fmaxf(b0, b1), fmaxf(b2, b3));
}

// ---- fused f32 -> bf16 convert: H (2M quads) + 4 weights (256K quads each) ----
__global__ __launch_bounds__(256) void cvt_all(const float* __restrict__ H,
        const float* __restrict__ Wq, const float* __restrict__ Wk,
        const float* __restrict__ Wv, const float* __restrict__ Wo,
        u16* __restrict__ Hb, u16* __restrict__ Wqb, u16* __restrict__ Wkb,
        u16* __restrict__ Wvb, u16* __restrict__ Wob) {
    int i = blockIdx.x * blockDim.x + threadIdx.x;   // quad index
    const float* s; u16* d; int o;
    if (i < 2097152) { s = H; d = Hb; o = i; }
    else {
        int j = i - 2097152;
        int a = j >> 18; o = j & 262143;
        s = a == 0 ? Wq : a == 1 ? Wk : a == 2 ? Wv : Wo;
        d = a == 0 ? Wqb : a == 1 ? Wkb : a == 2 ? Wvb : Wob;
    }
    f32x4 f = ((const f32x4*)s)[o];
    u32x2 v;
    v[0] = cvt_pk_bf16(f[0], f[1]);
    v[1] = cvt_pk_bf16(f[2], f[3]);
    ((u32x2*)d)[o] = v;
}

// ---- fused QKV GEMM: C[m][n] = sum_k A[m][k]*B[n][k]; XCD-banded m ----
// remap: xcd owns contiguous 8-m-tile band (A slice 2MB L2-resident), sweeps 24 (which,n)
__global__ __launch_bounds__(256) void gemm_qkv(const u16* __restrict__ A,
        const u16* __restrict__ B0, const u16* __restrict__ B1, const u16* __restrict__ B2,
        const float* __restrict__ c0, const float* __restrict__ c1, const float* __restrict__ c2,
        u16* __restrict__ O0, u16* __restrict__ O1, u16* __restrict__ O2) {
    __shared__ __align__(16) u16 As[2][128 * 64];
    __shared__ __align__(16) u16 Bs[2][128 * 64];
    const int tid  = threadIdx.x;
    const int w    = tid >> 6, lane = tid & 63;
    const int l15  = lane & 15, g = lane >> 4;
    const int wr   = w >> 1, wc = w & 1;
    // XCD-locality remap (dispatch-linear id, xcd = lin % 8 -- validated R8)
    const int lin  = blockIdx.x + blockIdx.y * 24;
    const int xcd  = lin & 7, q = lin >> 3;
    const int mt   = (xcd << 3) | (q & 7);
    const int r2   = q >> 3;            // 0..23
    const int which = r2 >> 3;          // 0..2
    const int nt   = r2 & 7;            // 0..7
    const int bm0  = mt * 128, bn0 = nt * 128;
    const u16* Bp     = which == 0 ? B0 : which == 1 ? B1 : B2;
    const float* bias = which == 0 ? c0 : which == 1 ? c1 : c2;
    u16* outp         = which == 0 ? O0 : which == 1 ? O1 : O2;
    const float scale = which == 0 ? 0.18033688011112042f : 1.0f;  // (1/8)*log2(e)

    const u16* asrc[4]; const u16* bsrc[4];
#pragma unroll
    for (int i = 0; i < 4; ++i) {
        int c = (w * 4 + i) * 64 + lane;
        int row = c >> 3, kc = (c & 7) ^ (row & 7);
        asrc[i] = A  + (size_t)(bm0 + row) * 1024 + kc * 8;
        bsrc[i] = Bp + (size_t)(bn0 + row) * 1024 + kc * 8;
    }
    auto stage = [&](int buf, int kt) {
#pragma unroll
        for (int i = 0; i < 4; ++i) {
            gload_lds16(asrc[i] + kt * 64, &As[buf][(w * 4 + i) * 512]);
            gload_lds16(bsrc[i] + kt * 64, &Bs[buf][(w * 4 + i) * 512]);
        }
    };

    f32x4 acc[4][4] = {};
    stage(0, 0);

#pragma unroll 2
    for (int kt = 0; kt < 16; ++kt) {
        const int cur = kt & 1;
        if (kt < 15) {
            stage(cur ^ 1, kt + 1);
            asm volatile("s_waitcnt vmcnt(8)" ::: "memory");
        } else {
            asm volatile("s_waitcnt vmcnt(0)" ::: "memory");
        }
        __builtin_amdgcn_s_barrier();
        __builtin_amdgcn_sched_barrier(0);

#pragma unroll
        for (int kk = 0; kk < 2; ++kk) {
            s16x8 af[4], bf_[4];
#pragma unroll
            for (int mi = 0; mi < 4; ++mi) {
                int row = wr * 64 + mi * 16 + l15;
                af[mi] = *(const s16x8*)&As[cur][row * 64 + (((kk * 4 + g) ^ (row & 7)) << 3)];
            }
#pragma unroll
            for (int ni = 0; ni < 4; ++ni) {
                int row = wc * 64 + ni * 16 + l15;
                bf_[ni] = *(const s16x8*)&Bs[cur][row * 64 + (((kk * 4 + g) ^ (row & 7)) << 3)];
            }
#pragma unroll
            for (int mi = 0; mi < 4; ++mi)
#pragma unroll
                for (int ni = 0; ni < 4; ++ni)
                    acc[mi][ni] = __builtin_amdgcn_mfma_f32_16x16x32_bf16(af[mi], bf_[ni], acc[mi][ni], 0, 0, 0);
        }
        __builtin_amdgcn_sched_barrier(0);
        __builtin_amdgcn_s_barrier();
    }

#pragma unroll
    for (int mi = 0; mi < 4; ++mi) {
#pragma unroll
        for (int ni = 0; ni < 4; ++ni) {
            int ncol = bn0 + wc * 64 + ni * 16 + l15;
            float bv = bias[ncol];
#pragma unroll
            for (int r = 0; r < 4; ++r) {
                int m   = bm0 + wr * 64 + mi * 16 + g * 4 + r;
                float v = (acc[mi][ni][r] + bv) * scale;
                int b_ = m >> 11, s = m & 2047, h = ncol >> 6, d = ncol & 63;
                if (which == 2)
                    outp[(((size_t)(b_ * 16 + h)) * 64 + d) * 2048 + s] = f2bf(v);
                else
                    outp[(((size_t)(b_ * 16 + h)) * 2048 + s) * 64 + d] = f2bf(v);
            }
        }
    }
}

// ---- output GEMM: f32 out, linear [m][n]; XCD-banded m ----
__global__ __launch_bounds__(256) void gemm_out(const u16* __restrict__ A, const u16* __restrict__ B,
                                                const float* __restrict__ bias, float* __restrict__ outp) {
    __shared__ __align__(16) u16 As[2][128 * 64];
    __shared__ __align__(16) u16 Bs[2][128 * 64];
    const int tid  = threadIdx.x;
    const int w    = tid >> 6, lane = tid & 63;
    const int l15  = lane & 15, g = lane >> 4;
    const int wr   = w >> 1, wc = w & 1;
    // XCD remap: xcd owns 8-m-tile band (A 2MB) + all B (2MB) = 4MB L2
    const int lin  = blockIdx.x + blockIdx.y * 8;
    const int xcd  = lin & 7, q = lin >> 3;         // q 0..63
    const int mt   = (xcd << 3) | (q & 7);
    const int nt   = q >> 3;                        // 0..7
    const int bm0  = mt * 128, bn0 = nt * 128;

    const u16* asrc[4]; const u16* bsrc[4];
#pragma unroll
    for (int i = 0; i < 4; ++i) {
        int c = (w * 4 + i) * 64 + lane;
        int row = c >> 3, kc = (c & 7) ^ (row & 7);
        asrc[i] = A + (size_t)(bm0 + row) * 1024 + kc * 8;
        bsrc[i] = B + (size_t)(bn0 + row) * 1024 + kc * 8;
    }
    auto stage = [&](int buf, int kt) {
#pragma unroll
        for (int i = 0; i < 4; ++i) {
            gload_lds16(asrc[i] + kt * 64, &As[buf][(w * 4 + i) * 512]);
            gload_lds16(bsrc[i] + kt * 64, &Bs[buf][(w * 4 + i) * 512]);
        }
    };

    f32x4 acc[4][4] = {};
    stage(0, 0);

#pragma unroll 2
    for (int kt = 0; kt < 16; ++kt) {
        const int cur = kt & 1;
        if (kt < 15) {
            stage(cur ^ 1, kt + 1);
            asm volatile("s_waitcnt vmcnt(8)" ::: "memory");
        } else {
            asm volatile("s_waitcnt vmcnt(0)" ::: "memory");
        }
        __builtin_amdgcn_s_barrier();
        __builtin_amdgcn_sched_barrier(0);

#pragma unroll
        for (int kk = 0; kk < 2; ++kk) {
            s16x8 af[4], bf_[4];
#pragma unroll
            for (int mi = 0; mi < 4; ++mi) {
                int row = wr * 64 + mi * 16 + l15;
                af[mi] = *(const s16x8*)&As[cur][row * 64 + (((kk * 4 + g) ^ (row & 7)) << 3)];
            }
#pragma unroll
            for (int ni = 0; ni < 4; ++ni) {
                int row = wc * 64 + ni * 16 + l15;
                bf_[ni] = *(const s16x8*)&Bs[cur][row * 64 + (((kk * 4 + g) ^ (row & 7)) << 3)];
            }
#pragma unroll
            for (int mi = 0; mi < 4; ++mi)
#pragma unroll
                for (int ni = 0; ni < 4; ++ni)
                    acc[mi][ni] = __builtin_amdgcn_mfma_f32_16x16x32_bf16(af[mi], bf_[ni], acc[mi][ni], 0, 0, 0);
        }
        __builtin_amdgcn_sched_barrier(0);
        __builtin_amdgcn_s_barrier();
    }

#pragma unroll
    for (int mi = 0; mi < 4; ++mi) {
#pragma unroll
        for (int ni = 0; ni < 4; ++ni) {
            int ncol = bn0 + wc * 64 + ni * 16 + l15;
            float bv = bias[ncol];
#pragma unroll
            for (int r = 0; r < 4; ++r) {
                int m = bm0 + wr * 64 + mi * 16 + g * 4 + r;
                outp[(size_t)m * 1024 + ncol] = acc[mi][ni][r] + bv;
            }
        }
    }
}

// ---- flash attention: 32x32 MFMA, in-register P exchange, conflict-free LDS swizzle ----
// Q[bh][s][d] pre-scaled by log2e/8, K[bh][s][d], VT[bh][d][s] -> concat bf16 [b][s][e]
// LDS swizzle f(r) = ((r&3)<<1)|((r>>2)&1): bijective on 0..7; conflict-free for both
// consecutive-8 and quad-pair hi-half phasings of wave64 ds_read_b128.
__global__ __launch_bounds__(256, 4) void attn_kernel(const u16* __restrict__ Q, const u16* __restrict__ K,
                                                      const u16* __restrict__ VT, u16* __restrict__ C) {
    __shared__ __align__(16) u16 Ks[2][64 * 64];
    __shared__ __align__(16) u16 Vs[2][64 * 64];
    const int tid = threadIdx.x;
    const int w   = tid >> 6, lane = tid & 63;
    const int l31 = lane & 31, hi = lane >> 5;
    // XCD-locality remap: each bh's 16 q-tiles land on one XCD (xcd = wgid%8, validated)
    const int n   = blockIdx.x;
    const int bh  = (n & 7) + 8 * (n >> 7);
    const int qt  = (n >> 3) & 15;
    const u16* Qb = Q  + (size_t)bh * 2048 * 64;
    const u16* Kb = K  + (size_t)bh * 2048 * 64;
    const u16* Vb = VT + (size_t)bh * 64 * 2048;
    const int q0  = qt * 128 + w * 32;

    // Q B-frags: bq[kk][i] = Q[q0+l31][kk*16 + hi*8 + i]
    s16x8 bq[4];
#pragma unroll
    for (int kk = 0; kk < 4; ++kk)
        bq[kk] = *(const s16x8*)&Qb[(size_t)(q0 + l31) * 64 + kk * 16 + hi * 8];

    // staging sources (chunk swizzled with f), tiles: Ks [64 keys][64 d], Vs [64 d][64 keys]
    const u16* ksrc[2]; const u16* vsrc[2];
#pragma unroll
    for (int i = 0; i < 2; ++i) {
        int c = w * 128 + i * 64 + lane;
        int rt = c >> 3;
        int fr = ((rt & 3) << 1) | ((rt >> 2) & 1);
        int cc = (c & 7) ^ fr;
        ksrc[i] = Kb + (size_t)rt * 64 + cc * 8;
        vsrc[i] = Vb + (size_t)rt * 2048 + cc * 8;
    }
    auto stage = [&](int buf, int kt) {
        int kb = kt * 64;
#pragma unroll
        for (int i = 0; i < 2; ++i) {
            gload_lds16(ksrc[i] + (size_t)kb * 64, &Ks[buf][(w * 128 + i * 64) * 8]);
            gload_lds16(vsrc[i] + kb,              &Vs[buf][(w * 128 + i * 64) * 8]);
        }
    };

    const int frl = ((l31 & 3) << 1) | ((l31 >> 2) & 1);   // f(row&7) for row = l31 / 32+l31

    float m_ = -1e30f, l_ = 0.f;     // row state; l_ lane-local (this hi-half's keys)
    f32x16 accO[2] = {};             // accO[dt][r] = O[q=l31][d=dt*32+crow(r,hi)]
    stage(0, 0);

#pragma unroll 2
    for (int kt = 0; kt < 32; ++kt) {
        const int cur = kt & 1;
        if (kt < 31) {
            stage(cur ^ 1, kt + 1);
            asm volatile("s_waitcnt vmcnt(4)" ::: "memory");
        } else {
            asm volatile("s_waitcnt vmcnt(0)" ::: "memory");
        }
        __builtin_amdgcn_s_barrier();
        __builtin_amdgcn_sched_barrier(0);

        // QK^T: sc covers keys 0..63 for q=l31
        f32x16 sc0 = {}, sc1 = {};
        __builtin_amdgcn_s_setprio(1);
#pragma unroll
        for (int kk = 0; kk < 4; ++kk) {
            int ch = (kk * 2 + hi) ^ frl;
            s16x8 ak0 = *(const s16x8*)&Ks[cur][(l31)      * 64 + (ch << 3)];
            s16x8 ak1 = *(const s16x8*)&Ks[cur][(32 + l31) * 64 + (ch << 3)];
            sc0 = __builtin_amdgcn_mfma_f32_32x32x16_bf16(ak0, bq[kk], sc0, 0, 0, 0);
            sc1 = __builtin_amdgcn_mfma_f32_32x32x16_bf16(ak1, bq[kk], sc1, 0, 0, 0);
        }
        __builtin_amdgcn_s_setprio(0);

        // exact online softmax (exp2 domain), row q across lane pair (l31, l31+32)
        float t = fmaxf(vmax16(sc0), vmax16(sc1));
        t = fmaxf(t, __shfl_xor(t, 32));
        const bool grow = __any(t > m_);
        if (grow) {
            float mn    = fmaxf(m_, t);
            float alpha = __builtin_amdgcn_exp2f(m_ - mn);
            m_ = mn;
            l_ *= alpha;
#pragma unroll
            for (int r = 0; r < 16; ++r) { accO[0][r] *= alpha; accO[1][r] *= alpha; }
        }

#pragma unroll
        for (int r = 0; r < 16; ++r) sc0[r] = __builtin_amdgcn_exp2f(sc0[r] - m_);
#pragma unroll
        for (int r = 0; r < 16; ++r) sc1[r] = __builtin_amdgcn_exp2f(sc1[r] - m_);
        {
            float s0 = 0.f, s1 = 0.f, s2 = 0.f, s3 = 0.f;
#pragma unroll
            for (int r = 0; r < 16; r += 4) {
                s0 += sc0[r]; s1 += sc0[r + 1]; s2 += sc0[r + 2]; s3 += sc0[r + 3];
                s0 += sc1[r]; s1 += sc1[r + 1]; s2 += sc1[r + 2]; s3 += sc1[r + 3];
            }
            l_ += (s0 + s1) + (s2 + s3);
        }

        // pack P to bf16 pairs: c[kj][rp] = {p[2rp], p[2rp+1]}
        u32 c[2][8];
#pragma unroll
        for (int rp = 0; rp < 8; ++rp) {
            c[0][rp] = cvt_pk_bf16(sc0[2 * rp], sc0[2 * rp + 1]);
            c[1][rp] = cvt_pk_bf16(sc1[2 * rp], sc1[2 * rp + 1]);
        }
        // assemble PV B-frags: pf[ks].u32[j] = P[q][ks*16 + hi*8 + 2j .. +1]
        s16x8 pf[4];
#pragma unroll
        for (int ks = 0; ks < 4; ++ks) {
            int kj = ks >> 1, base = (ks & 1) * 4;
            u32 a0 = c[kj][base + 0], b0 = c[kj][base + 2];
            u32 a1 = c[kj][base + 1], b1 = c[kj][base + 3];
            permswap(a0, b0);
            permswap(a1, b1);
            u32x4 pv; pv[0] = a0; pv[1] = a1; pv[2] = b0; pv[3] = b1;
            pf[ks] = __builtin_bit_cast(s16x8, pv);
        }

        // O^T += V^T . P^T
        __builtin_amdgcn_s_setprio(1);
#pragma unroll
        for (int ks = 0; ks < 4; ++ks) {
            int ch = (ks * 2 + hi) ^ frl;
            s16x8 av0 = *(const s16x8*)&Vs[cur][(l31)      * 64 + (ch << 3)];
            s16x8 av1 = *(const s16x8*)&Vs[cur][(32 + l31) * 64 + (ch << 3)];
            accO[0] = __builtin_amdgcn_mfma_f32_32x32x16_bf16(av0, pf[ks], accO[0], 0, 0, 0);
            accO[1] = __builtin_amdgcn_mfma_f32_32x32x16_bf16(av1, pf[ks], accO[1], 0, 0, 0);
        }
        __builtin_amdgcn_s_setprio(0);
        __builtin_amdgcn_sched_barrier(0);
        __builtin_amdgcn_s_barrier();
    }

    // epilogue: O[q][d] = accO/l ; d = dt*32 + 8*rq + 4*hi + e
    l_ += __shfl_xor(l_, 32);
    float inv = 1.0f / l_;
    const int b_ = bh >> 4, h = bh & 15;
    const int s  = q0 + l31;
#pragma unroll
    for (int dt = 0; dt < 2; ++dt)
#pragma unroll
        for (int rq = 0; rq < 4; ++rq) {
            int d0 = dt * 32 + 8 * rq + 4 * hi;
            u32x2 v;
            v[0] = cvt_pk_bf16(accO[dt][4 * rq] * inv,     accO[dt][4 * rq + 1] * inv);
            v[1] = cvt_pk_bf16(accO[dt][4 * rq + 2] * inv, accO[dt][4 * rq + 3] * inv);
            *(u32x2*)&C[((size_t)(b_ * 2048 + s)) * 1024 + h * 64 + d0] = v;
        }
}

extern "C" void kernel_launch(void* const* d_in, const int* in_sizes, int n_in,
                              void* d_out, int out_size, void* d_ws, size_t ws_size,
                              hipStream_t stream) {
    const float* H  = (const float*)d_in[0];
    const float* Wq = (const float*)d_in[1];
    const float* bq = (const float*)d_in[2];
    const float* Wk = (const float*)d_in[3];
    const float* bk = (const float*)d_in[4];
    const float* Wv = (const float*)d_in[5];
    const float* bv = (const float*)d_in[6];
    const float* Wo = (const float*)d_in[7];
    const float* bo = (const float*)d_in[8];

    char*  ws  = (char*)d_ws;
    size_t off = 0;
    auto alloc = [&](size_t elems) { u16* p = (u16*)(ws + off); off += elems * 2; return p; };
    u16* Hb  = alloc((size_t)8192 * 1024);
    u16* Wqb = alloc((size_t)1024 * 1024);
    u16* Wkb = alloc((size_t)1024 * 1024);
    u16* Wvb = alloc((size_t)1024 * 1024);
    u16* Wob = alloc((size_t)1024 * 1024);
    u16* Qs  = alloc((size_t)8192 * 1024);
    u16* Ks  = alloc((size_t)8192 * 1024);
    u16* VTs = alloc((size_t)8192 * 1024);
    u16* Cc  = alloc((size_t)8192 * 1024);

    cvt_all<<<12288, 256, 0, stream>>>(H, Wq, Wk, Wv, Wo, Hb, Wqb, Wkb, Wvb, Wob);

    dim3 gq(24, 64);
    gemm_qkv<<<gq, 256, 0, stream>>>(Hb, Wqb, Wkb, Wvb, bq, bk, bv, Qs, Ks, VTs);

    attn_kernel<<<1024, 256, 0, stream>>>(Qs, Ks, VTs, Cc);

    dim3 gg(8, 64);
    gemm_out<<<gg, 256, 0, stream>>>(Cc, Wob, bo, (float*)d_out);
}